// Round 1
// baseline (131.683 us; speedup 1.0000x reference)
//
#include <hip/hip_runtime.h>

typedef __bf16 bf16x8 __attribute__((ext_vector_type(8)));
typedef float f32x4 __attribute__((ext_vector_type(4)));
typedef unsigned short u16x8 __attribute__((ext_vector_type(8)));

#define CC 256
#define HH 48
#define WW 64
#define NB 8
#define GW 21

// ---------------------------------------------------------------------------
// Prepass: [B,C,H,W] fp32 -> [B,H*W,C] bf16 (RNE). in1 additionally scaled by
// 2^-8 (exact in bf16) to fold the /sumelems into the product.
// Grid: 1536 blocks (768 per input), 256 threads. LDS transpose 32(s) x 256(c).
// ---------------------------------------------------------------------------
__global__ __launch_bounds__(256) void prep_kernel(const float* __restrict__ in1,
                                                   const float* __restrict__ in2,
                                                   unsigned short* __restrict__ o1,
                                                   unsigned short* __restrict__ o2)
{
    __shared__ float lds[CC * 33];   // [c][s] stride 33 -> conflict-free both phases
    int blk = blockIdx.x;
    int sel  = (blk >= 768);
    int blk2 = sel ? blk - 768 : blk;
    int b  = blk2 & 7;
    int st = blk2 >> 3;              // 0..95 spatial tile
    int s0 = st * 32;
    const float* src = sel ? in2 : in1;
    unsigned short* dst = sel ? o2 : o1;
    float scale = sel ? 1.0f : (1.0f / 256.0f);

    int t = threadIdx.x;
    int sidx = t & 31;
    int cbase = t >> 5;              // 0..7
    const float* sb = src + (size_t)b * CC * (HH * WW) + s0;
    #pragma unroll 4
    for (int p = 0; p < 32; ++p) {
        int c = cbase + p * 8;
        lds[c * 33 + sidx] = sb[(size_t)c * (HH * WW) + sidx] * scale;
    }
    __syncthreads();

    int cp  = t & 127;               // c-pair index
    int sw0 = t >> 7;                // 0..1
    unsigned short* db = dst + ((size_t)b * (HH * WW) + s0) * CC;
    #pragma unroll 4
    for (int p = 0; p < 16; ++p) {
        int s = sw0 + p * 2;
        float f0 = lds[(2 * cp) * 33 + s];
        float f1 = lds[(2 * cp + 1) * 33 + s];
        unsigned u0 = __builtin_bit_cast(unsigned, f0);
        u0 += 0x7fffu + ((u0 >> 16) & 1u);
        unsigned u1 = __builtin_bit_cast(unsigned, f1);
        u1 += 0x7fffu + ((u1 >> 16) & 1u);
        unsigned packed = (u0 >> 16) | (u1 & 0xffff0000u);
        *(unsigned*)(db + (size_t)s * CC + 2 * cp) = packed;
    }
}

// ---------------------------------------------------------------------------
// Main: block = (b, ysrc, j-group). For valid ysrc: banded GEMM
//   D[x][x'] = sum_c in1T[b,y,x,c] * in2T[b,ysrc,x',c],  y = ysrc - dy(j)
// via mfma_f32_16x16x32_bf16; band extraction out[...] = D[x][x+dx].
// For OOB ysrc: zero-fill the corresponding output rows.
// Grid: 8 * 88 * 3 = 2112 blocks, 256 threads (4 waves, 2 rows/wave).
// ---------------------------------------------------------------------------
__global__ __launch_bounds__(256, 2) void corr_kernel(const unsigned short* __restrict__ in1T,
                                                      const unsigned short* __restrict__ in2T,
                                                      float* __restrict__ out)
{
    __shared__ unsigned char smem[36864];          // B-stage (33792B) then D-transpose (36864B)
    unsigned short* Bl = (unsigned short*)smem;    // [64][264] bf16, pad breaks bank stride

    int blk  = blockIdx.x;
    int b    = blk & 7;                            // batch == XCD affinity (round-robin)
    int rest = blk >> 3;
    int ysrc = (rest % 88) - 20;                   // in2 source row, may be OOB
    int g    = rest / 88;                          // 0..2  -> j in [8g, min(8g+8,21))
    int jlo  = g * 8;
    int jhi  = (jlo + 8 < GW) ? jlo + 8 : GW;
    int tid  = threadIdx.x;

    if (ysrc < 0 || ysrc >= HH) {
        // zero-fill: output rows whose in2 source row is out of bounds
        for (int j = jlo; j < jhi; ++j) {
            int yo = ysrc - 2 * (j - 10);
            if (yo < 0 || yo >= HH) continue;
            float* obase = out + (((size_t)b * 441 + (size_t)j * GW) * HH + yo) * WW;
            for (int idx = tid; idx < GW * WW; idx += 256) {
                int jx = idx >> 6;
                int x  = idx & 63;
                obase[(size_t)jx * (HH * WW) + x] = 0.0f;
            }
        }
        return;
    }

    // ---- stage B row (in2T[b, ysrc, :, :]) into padded LDS ----
    {
        const unsigned short* b2 = in2T + ((size_t)(b * HH + ysrc) * WW) * CC;
        for (int i = tid; i < 64 * 32; i += 256) {
            int xp = i >> 5;
            int co = (i & 31) * 8;
            *(u16x8*)(Bl + xp * 264 + co) = *(const u16x8*)(b2 + (size_t)xp * CC + co);
        }
    }
    __syncthreads();

    int w    = tid >> 6;
    int lane = tid & 63;
    int l15  = lane & 15;
    int q    = lane >> 4;

    int j0 = jlo + 2 * w;
    int rv[2];
    int yout[2];
    #pragma unroll
    for (int r = 0; r < 2; ++r) {
        int j  = j0 + r;
        int yo = ysrc - 2 * (j - 10);
        rv[r]   = (j < jhi) && (yo >= 0) && (yo < HH);
        yout[r] = yo;
    }

    f32x4 acc[2][4][4];
    #pragma unroll
    for (int r = 0; r < 2; ++r)
        #pragma unroll
        for (int mt = 0; mt < 4; ++mt)
            #pragma unroll
            for (int nt = 0; nt < 4; ++nt)
                acc[r][mt][nt] = (f32x4){0.f, 0.f, 0.f, 0.f};

    // A fragment base: lane holds A[m = l15][k = q*8 + j] for its m-tile
    const unsigned short* abase[2];
    #pragma unroll
    for (int r = 0; r < 2; ++r)
        abase[r] = rv[r]
            ? (in1T + ((size_t)((b * HH + yout[r]) * WW) + l15) * CC + q * 8)
            : in1T;   // dummy, never loaded

    const unsigned short* bptr = Bl + l15 * 264 + q * 8;   // B[k = q*8+j][n = l15]

    for (int ks = 0; ks < 8; ++ks) {
        int c0 = ks * 32;
        bf16x8 bf[4];
        #pragma unroll
        for (int nt = 0; nt < 4; ++nt)
            bf[nt] = *(const bf16x8*)(bptr + nt * 16 * 264 + c0);
        #pragma unroll
        for (int r = 0; r < 2; ++r) {
            if (!rv[r]) continue;
            bf16x8 af[4];
            #pragma unroll
            for (int mt = 0; mt < 4; ++mt)
                af[mt] = *(const bf16x8*)(abase[r] + mt * 16 * CC + c0);
            #pragma unroll
            for (int mt = 0; mt < 4; ++mt)
                #pragma unroll
                for (int nt = 0; nt < 4; ++nt)
                    acc[r][mt][nt] = __builtin_amdgcn_mfma_f32_16x16x32_bf16(
                        af[mt], bf[nt], acc[r][mt][nt], 0, 0, 0);
        }
    }

    __syncthreads();   // B-stage LDS is dead; reuse region for D-transpose

    // Wave-private D^T buffer: [col 0..63][row-in-half 0..31], stride 36 dwords
    float* dtw = (float*)smem + w * 2304;
    int xl  = lane & 31;
    int jxp = lane >> 5;

    #pragma unroll
    for (int r = 0; r < 2; ++r) {
        if (!rv[r]) continue;
        int j = j0 + r;
        float* orow = out + (((size_t)b * 441 + (size_t)j * GW) * HH + yout[r]) * WW;
        #pragma unroll
        for (int h = 0; h < 2; ++h) {
            // dump D rows [32h, 32h+32): acc reg quad -> 4 consecutive rows => b128
            #pragma unroll
            for (int mt2 = 0; mt2 < 2; ++mt2) {
                int mt = 2 * h + mt2;
                #pragma unroll
                for (int nt = 0; nt < 4; ++nt)
                    *(f32x4*)(dtw + (nt * 16 + l15) * 36 + mt2 * 16 + q * 4) = acc[r][mt][nt];
            }
            // band extraction: lane = (x-local, jx-parity); coalesced 128B stores
            int x = h * 32 + xl;
            #pragma unroll
            for (int jj = 0; jj < 11; ++jj) {
                int jx = 2 * jj + jxp;
                if (jx >= GW) continue;
                int dx   = 2 * (jx - 10);
                int colx = x + dx;
                float v = (colx >= 0 && colx < WW) ? dtw[colx * 36 + xl] : 0.0f;
                orow[(size_t)jx * (HH * WW) + x] = v;
            }
        }
    }
}

extern "C" void kernel_launch(void* const* d_in, const int* in_sizes, int n_in,
                              void* d_out, int out_size, void* d_ws, size_t ws_size,
                              hipStream_t stream)
{
    (void)in_sizes; (void)n_in; (void)out_size; (void)ws_size;
    const float* in1 = (const float*)d_in[0];
    const float* in2 = (const float*)d_in[1];
    float* out = (float*)d_out;

    // d_ws layout: in1T bf16 [8][48*64][256] then in2T same (25.2 MB total)
    unsigned short* in1T = (unsigned short*)d_ws;
    unsigned short* in2T = in1T + (size_t)NB * HH * WW * CC;

    prep_kernel<<<dim3(1536), dim3(256), 0, stream>>>(in1, in2, in1T, in2T);
    corr_kernel<<<dim3(2112), dim3(256), 0, stream>>>(in1T, in2T, out);
}